// Round 6
// baseline (89.629 us; speedup 1.0000x reference)
//
#include <hip/hip_runtime.h>
#include <math.h>

#define NH 512
#define NO 512
#define BT_TOT 256
#define HID 64
#define OUTD 128

typedef float float2v __attribute__((ext_vector_type(2)));

__device__ __forceinline__ float wave_sum(float v) {
    #pragma unroll
    for (int off = 32; off > 0; off >>= 1) v += __shfl_xor(v, off, 64);
    return v;
}

// 1024 threads per bt. Q=8 register blocking + packed-fp32 (v_pk_fma_f32) distance math.
// SoA LDS tables: Ox = -2*ox, ..., Ow = ||o||^2 (same for H).
// acc(j, m) = Ow[m] + px_j*Ox[m] + py_j*Oy[m] + pz_j*Oz[m]  ( = d2 - ||h_j||^2 )
// Fixed j => argmin/min over acc == argmin/min over d2. Exact d2 recovered at combine.
// Comparison sequence identical to previous round (strict <, ascending index) => bit-identical.
__global__ __launch_bounds__(1024) void ie_kernel(
    const float* __restrict__ h_in, const float* __restrict__ o_in,
    const float* __restrict__ sh_in,
    const float* __restrict__ W1, const float* __restrict__ b1,
    const float* __restrict__ W2, const float* __restrict__ b2,
    float* __restrict__ out)
{
    __shared__ __align__(16) float Ox[NO], Oy[NO], Oz[NO], Ow[NO];  // 8 KB
    __shared__ __align__(16) float Hx[NH], Hy[NH], Hz[NH], Hw[NH];  // 8 KB
    __shared__ float p1val[8 * NH];    // 16 KB  [substream][human]
    __shared__ int   p1idx[8 * NH];    // 16 KB
    __shared__ float p2val[8 * NO];    // 16 KB
    __shared__ float sdm[2][NH];       // 4 KB (double-buffered sort exchange)
    __shared__ float wred[5][8];
    __shared__ float feats[16];
    __shared__ float hidden[HID];

    const int bt = blockIdx.x, t = threadIdx.x;
    const int wave = t >> 6, lane = t & 63;

    // ---- build SoA tables in LDS ----
    if (t < NO) {
        const float* op = o_in + ((size_t)bt * NO + t) * 3;
        float x = op[0], y = op[1], z = op[2];
        Ox[t] = -2.f * x; Oy[t] = -2.f * y; Oz[t] = -2.f * z;
        Ow[t] = x * x + y * y + z * z;
    } else {
        const int i = t - NO;
        const float* hp = h_in + ((size_t)bt * NH + i) * 3;
        float x = hp[0], y = hp[1], z = hp[2];
        Hx[i] = -2.f * x; Hy[i] = -2.f * y; Hz[i] = -2.f * z;
        Hw[i] = x * x + y * y + z * z;
    }
    __syncthreads();

    // ---- main distance loops (Q=8 per thread, packed pairs) ----
    if (t < 512) {
        const int l = t & 63, wv = t >> 6;
        const int obase = wv << 6;
        float qx[8], qy[8], qz[8], bb[8];
        int   bi[8];
        #pragma unroll
        for (int j = 0; j < 8; j++) {
            const int hi = l + 64 * j;
            qx[j] = -0.5f * Hx[hi]; qy[j] = -0.5f * Hy[hi]; qz[j] = -0.5f * Hz[hi];
            bb[j] = 1e30f; bi[j] = obase;
        }
        for (int n = 0; n < 64; n += 4) {
            float4 X = *(const float4*)&Ox[obase + n];
            float4 Y = *(const float4*)&Oy[obase + n];
            float4 Z = *(const float4*)&Oz[obase + n];
            float4 W = *(const float4*)&Ow[obase + n];
            float2v xlo = {X.x, X.y}, xhi = {X.z, X.w};
            float2v ylo = {Y.x, Y.y}, yhi = {Y.z, Y.w};
            float2v zlo = {Z.x, Z.y}, zhi = {Z.z, Z.w};
            float2v wlo = {W.x, W.y}, whi = {W.z, W.w};
            #pragma unroll
            for (int j = 0; j < 8; j++) {
                float2v qxs = {qx[j], qx[j]}, qys = {qy[j], qy[j]}, qzs = {qz[j], qz[j]};
                float2v dlo = __builtin_elementwise_fma(qzs, zlo,
                               __builtin_elementwise_fma(qys, ylo,
                                __builtin_elementwise_fma(qxs, xlo, wlo)));
                float2v dhi = __builtin_elementwise_fma(qzs, zhi,
                               __builtin_elementwise_fma(qys, yhi,
                                __builtin_elementwise_fma(qxs, xhi, whi)));
                // strict < , ascending index => first-index tie-break (same as before)
                if (dlo.x < bb[j]) { bb[j] = dlo.x; bi[j] = obase + n;     }
                if (dlo.y < bb[j]) { bb[j] = dlo.y; bi[j] = obase + n + 1; }
                if (dhi.x < bb[j]) { bb[j] = dhi.x; bi[j] = obase + n + 2; }
                if (dhi.y < bb[j]) { bb[j] = dhi.y; bi[j] = obase + n + 3; }
            }
        }
        #pragma unroll
        for (int j = 0; j < 8; j++) {
            p1val[wv * NH + l + 64 * j] = bb[j];
            p1idx[wv * NH + l + 64 * j] = bi[j];
        }
    } else {
        const int u = t - 512, l = u & 63, wv = u >> 6;
        const int nbase = wv << 6;
        float qx[8], qy[8], qz[8];
        float2v cc2[8];
        #pragma unroll
        for (int j = 0; j < 8; j++) {
            const int oi = l + 64 * j;
            qx[j] = -0.5f * Ox[oi]; qy[j] = -0.5f * Oy[oi]; qz[j] = -0.5f * Oz[oi];
            cc2[j] = (float2v){1e30f, 1e30f};
        }
        for (int n = 0; n < 64; n += 4) {
            float4 X = *(const float4*)&Hx[nbase + n];
            float4 Y = *(const float4*)&Hy[nbase + n];
            float4 Z = *(const float4*)&Hz[nbase + n];
            float4 W = *(const float4*)&Hw[nbase + n];
            float2v xlo = {X.x, X.y}, xhi = {X.z, X.w};
            float2v ylo = {Y.x, Y.y}, yhi = {Y.z, Y.w};
            float2v zlo = {Z.x, Z.y}, zhi = {Z.z, Z.w};
            float2v wlo = {W.x, W.y}, whi = {W.z, W.w};
            #pragma unroll
            for (int j = 0; j < 8; j++) {
                float2v qxs = {qx[j], qx[j]}, qys = {qy[j], qy[j]}, qzs = {qz[j], qz[j]};
                float2v dlo = __builtin_elementwise_fma(qzs, zlo,
                               __builtin_elementwise_fma(qys, ylo,
                                __builtin_elementwise_fma(qxs, xlo, wlo)));
                float2v dhi = __builtin_elementwise_fma(qzs, zhi,
                               __builtin_elementwise_fma(qys, yhi,
                                __builtin_elementwise_fma(qxs, xhi, whi)));
                cc2[j] = __builtin_elementwise_min(cc2[j], dlo);
                cc2[j] = __builtin_elementwise_min(cc2[j], dhi);
            }
        }
        #pragma unroll
        for (int j = 0; j < 8; j++)
            p2val[wv * NO + l + 64 * j] = fminf(cc2[j].x, cc2[j].y);
    }
    __syncthreads();

    // ---- combine 8 substream partials per point, per-point features ----
    float v = 0.f;          // dmin_h for sort (t<512)
    float w_t = 0.f, dx = 0.f, dy = 0.f, dz = 0.f, dmo_t = 0.f;
    if (t < 512) {
        float best = p1val[t]; int bm = p1idx[t];
        #pragma unroll
        for (int w = 1; w < 8; w++) {
            float pv = p1val[w * NH + t];
            int   pi = p1idx[w * NH + t];
            if (pv < best) { best = pv; bm = pi; }  // strict <, ascending w => lowest index on tie
        }
        const float px = -0.5f * Hx[t], py = -0.5f * Hy[t], pz = -0.5f * Hz[t];
        const float dmin_t = sqrtf(fmaxf(Hw[t] + best, 0.f));
        const float ox = -0.5f * Ox[bm], oy = -0.5f * Oy[bm], oz = -0.5f * Oz[bm];
        const float vx = ox - px, vy = oy - py, vz = oz - pz;
        const float n2 = vx * vx + vy * vy + vz * vz;
        const float inv = 1.0f / sqrtf(fmaxf(n2, 1e-6f));
        w_t = expf(-dmin_t * 20.0f) * sh_in[(size_t)bt * NH + t];
        dx = vx * inv; dy = vy * inv; dz = vz * inv;
        v = dmin_t;
    } else {
        const int o = t - 512;
        float c = p2val[o];
        #pragma unroll
        for (int w = 1; w < 8; w++) c = fminf(c, p2val[w * NO + o]);
        dmo_t = sqrtf(fmaxf(Ow[o] + c, 0.f));
    }

    // ---- reductions set 1 ----
    if (t < 512) {
        float s0 = wave_sum(w_t), s1 = wave_sum(dx), s2 = wave_sum(dy), s3 = wave_sum(dz);
        if (lane == 0) { wred[0][wave] = s0; wred[1][wave] = s1; wred[2][wave] = s2; wred[3][wave] = s3; }
    } else {
        float s4 = wave_sum(dmo_t);
        if (lane == 0) wred[4][wave - 8] = s4;
    }
    __syncthreads();
    if (t < 5) {
        float s = 0.f;
        #pragma unroll
        for (int w = 0; w < 8; w++) s += wred[t][w];
        const int slot[5] = {5, 6, 7, 8, 9};
        feats[slot[t]] = s * (1.0f / 512.0f);
    }

    // ---- bitonic sort of dmin_h (t<512); shuffles for j<64, double-buffered LDS for j>=64 ----
    int buf = 0;
    for (int k2 = 2; k2 <= 512; k2 <<= 1) {
        for (int j = k2 >> 1; j > 0; j >>= 1) {
            float pv;
            if (j >= 64) {
                if (t < 512) sdm[buf][t] = v;
                __syncthreads();
                pv = (t < 512) ? sdm[buf][t ^ j] : 0.f;
                buf ^= 1;  // next LDS stage uses the other buffer; no second barrier needed
            } else {
                pv = __shfl_xor(v, j, 64);
            }
            if (t < 512) {
                const bool keepmin = (((t & k2) == 0) == ((t & j) == 0));
                v = keepmin ? fminf(v, pv) : fmaxf(v, pv);
            }
        }
    }

    // ---- reductions set 2: prefix means over sorted dmin_h ----
    if (t < 512) {
        float s0 = wave_sum(t < 102 ? v : 0.f);
        float s1 = wave_sum(t < 256 ? v : 0.f);
        float s2 = wave_sum(t < 410 ? v : 0.f);
        float s3 = wave_sum(v);
        if (lane == 0) { wred[0][wave] = s0; wred[1][wave] = s1; wred[2][wave] = s2; wred[3][wave] = s3; }
        if (t == 0) feats[1] = v;  // sorted min
    }
    __syncthreads();
    if (t < 4) {
        float s = 0.f;
        #pragma unroll
        for (int w = 0; w < 8; w++) s += wred[t][w];
        const int   slot[4]  = {2, 3, 4, 0};
        const float scale[4] = {1.f / 102.f, 1.f / 256.f, 1.f / 410.f, 1.f / 512.f};
        feats[slot[t]] = s * scale[t];
    }
    __syncthreads();

    // ---- fused MLP: 10 -> 64 (ReLU) -> 128 ----
    if (t < HID) {
        float acc = b1[t];
        #pragma unroll
        for (int i = 0; i < 10; i++) acc += feats[i] * W1[i * HID + t];
        hidden[t] = fmaxf(acc, 0.0f);
    }
    __syncthreads();
    if (t < OUTD) {
        float acc = b2[t];
        #pragma unroll
        for (int j = 0; j < HID; j++) acc += hidden[j] * W2[j * OUTD + t];
        out[(size_t)bt * OUTD + t] = acc;
    }
}

extern "C" void kernel_launch(void* const* d_in, const int* in_sizes, int n_in,
                              void* d_out, int out_size, void* d_ws, size_t ws_size,
                              hipStream_t stream) {
    (void)in_sizes; (void)n_in; (void)out_size; (void)d_ws; (void)ws_size;
    const float* h_in  = (const float*)d_in[0];
    const float* o_in  = (const float*)d_in[1];
    const float* sh_in = (const float*)d_in[2];
    // d_in[3] (s_o) is dead after the [:, :10] slice
    const float* W1 = (const float*)d_in[4];
    const float* b1 = (const float*)d_in[5];
    const float* W2 = (const float*)d_in[6];
    const float* b2 = (const float*)d_in[7];
    float* out = (float*)d_out;

    ie_kernel<<<BT_TOT, 1024, 0, stream>>>(h_in, o_in, sh_in, W1, b1, W2, b2, out);
}